// Round 5
// baseline (6117.422 us; speedup 1.0000x reference)
//
#include <hip/hip_runtime.h>
#include <hip/hip_cooperative_groups.h>
#include <stdint.h>

namespace cg = cooperative_groups;

#define B_    128
#define F_    4
#define V_    2048
#define D_    4096
#define DW    64      // D/64 bit-words per (b,f) row
#define VW    32      // V/64 bit-words per d column
#define ITERS 20
#define NKT   16      // K tiles of 128 over V=2048

typedef _Float16 half8 __attribute__((ext_vector_type(8)));
typedef float   floatx4 __attribute__((ext_vector_type(4)));

__device__ __forceinline__ void pack16(const float* __restrict__ x, int t,
                                       uint16_t* __restrict__ dst) {
    const float4* p = (const float4*)(x + (size_t)t * 16);
    unsigned m = 0;
    #pragma unroll
    for (int j = 0; j < 4; ++j) {
        float4 v = p[j];
        m |= (v.x < 0.0f ? 1u : 0u) << (4 * j + 0);
        m |= (v.y < 0.0f ? 1u : 0u) << (4 * j + 1);
        m |= (v.z < 0.0f ? 1u : 0u) << (4 * j + 2);
        m |= (v.w < 0.0f ? 1u : 0u) << (4 * j + 3);
    }
    dst[t] = (uint16_t)m;
}

// ==================================================================
// Fused persistent cooperative kernel.  All phases are grid-stride
// over virtual block IDs, so any grid size (256/512) is correct.
// ==================================================================
__global__ __launch_bounds__(256, 2) void k_fused(
        const float* __restrict__ inputs, const float* __restrict__ inite,
        const float* __restrict__ cb, int* __restrict__ out,
        uint64_t* __restrict__ cb_bits, uint64_t* __restrict__ cbT,
        uint64_t* __restrict__ est_bits, uint64_t* __restrict__ in_bits,
        uint64_t* __restrict__ nbc, _Float16* __restrict__ simf,
        int* __restrict__ flags, int* __restrict__ keys)
{
    cg::grid_group grid = cg::this_grid();
    const int nblk = gridDim.x;
    const int bx = blockIdx.x, tid = threadIdx.x;
    const int gtid = bx * 256 + tid, gsz = nblk * 256;
    const int lane = tid & 63, wave = tid >> 6;
    const int lrow = lane & 15, lq = lane >> 4;
    const int wm = wave & 1, wn = wave >> 1;

    __shared__ __align__(16) uint64_t Bb[64 * VW];      // 16 KB B bit panel
    __shared__ __align__(16) _Float16 As[64 * 128];     // 16 KB A tile / scratch
    __shared__ int bd;

    // ------- phase 0: bit-pack inputs; zero flags/keys ------------------
    {
        uint16_t* cbb = (uint16_t*)cb_bits;
        for (int t = gtid; t < F_ * V_ * D_ / 16; t += gsz) pack16(cb, t, cbb);
        uint16_t* e16 = (uint16_t*)est_bits;
        for (int t = gtid; t < B_ * F_ * D_ / 16; t += gsz) pack16(inite, t, e16);
        uint16_t* i16 = (uint16_t*)in_bits;
        for (int t = gtid; t < B_ * D_ / 16; t += gsz) pack16(inputs, t, i16);
        if (gtid < ITERS) flags[gtid] = 0;
        if (gtid >= 32 && gtid < 32 + B_ * F_) keys[gtid - 32] = 0;
    }
    grid.sync();

    // ------- phase 1: transpose cb; init nbc = in^e0^e1^e2^e3 -----------
    for (int t = gtid; t < B_ * DW; t += gsz) {
        int b = t >> 6, w = t & 63;
        const uint64_t* e = est_bits + (size_t)b * F_ * DW;
        nbc[t] = in_bits[t] ^ e[w] ^ e[DW + w] ^ e[2 * DW + w] ^ e[3 * DW + w];
    }
    for (int u = bx; u < 2048; u += nblk) {        // whole block per unit
        int vw = u & 31, dwg = (u >> 5) & 15, f = u >> 9;
        int dw = dwg * 4 + wave;
        uint64_t w = cb_bits[((size_t)f * V_ + vw * 64 + lane) * DW + dw];
        uint64_t r = 0;
        for (int d2 = 0; d2 < 64; ++d2) {
            uint64_t m = __ballot((unsigned)((w >> d2) & 1));
            if (lane == d2) r = m;
        }
        cbT[((size_t)f * D_ + dw * 64 + lane) * VW + vw] = r;
    }
    grid.sync();

    volatile int* vflags = (volatile int*)flags;

    for (int it = 0; it < ITERS; ++it) {
        // ------- sim: sim[b,v] = 2048 - popc(nbc ^ est_f ^ cb) ----------
        for (int vb = bx; vb < 512; vb += nblk) {
            int sf = vb & 3, sbg = (vb >> 2) & 15, svt = vb >> 6;
            int v = svt * 256 + tid;
            const uint64_t* cbrow = cb_bits + ((size_t)sf * V_ + v) * DW;
            int acc[8];
            #pragma unroll
            for (int bb = 0; bb < 8; ++bb) acc[bb] = 2048;
            #pragma unroll 1
            for (int h = 0; h < 2; ++h) {
                ulonglong2 c[16];
                #pragma unroll
                for (int j = 0; j < 16; ++j) c[j] = *(const ulonglong2*)&cbrow[h * 32 + 2 * j];
                #pragma unroll
                for (int bb = 0; bb < 8; ++bb) {
                    int b = sbg * 8 + bb;
                    const uint64_t* np = nbc + (size_t)b * DW + h * 32;       // uniform
                    const uint64_t* ep = est_bits + ((size_t)b * F_ + sf) * DW + h * 32;
                    int s = 0;
                    #pragma unroll
                    for (int j = 0; j < 16; ++j) {
                        uint64_t n0 = np[2 * j]     ^ ep[2 * j];
                        uint64_t n1 = np[2 * j + 1] ^ ep[2 * j + 1];
                        s += __popcll(c[j].x ^ n0) + __popcll(c[j].y ^ n1);
                    }
                    acc[bb] -= s;
                }
            }
            #pragma unroll
            for (int bb = 0; bb < 8; ++bb)
                simf[((size_t)sf * B_ + sbg * 8 + bb) * V_ + v] = (_Float16)acc[bb];
        }
        grid.sync();

        // ------- gemm: est = sign(sim @ cb^T), BM=64 BN=64 --------------
        for (int vb = bx; vb < 512; vb += nblk) {
            int gf = vb & 3, gmt = (vb >> 2) & 1, gnt = vb >> 3;
            int gm0 = gmt * 64;
            __syncthreads();                       // protect Bb/As reuse
            if (tid == 0) bd = 0;
            const uint64_t* bsrc = cbT + ((size_t)gf * D_ + gnt * 64) * VW;
            #pragma unroll
            for (int p = 0; p < 4; ++p) {
                int chunk = p * 256 + tid;
                int dloc = chunk >> 4, cw = chunk & 15;
                ulonglong2 val = *(const ulonglong2*)&bsrc[dloc * VW + cw * 2];
                *(ulonglong2*)&Bb[dloc * VW + ((cw ^ (dloc & 15)) * 2)] = val;
            }
            const _Float16* Ab = simf + (size_t)gf * B_ * V_ + (size_t)gm0 * V_;
            int arow = tid >> 4, acol = tid & 15;
            half8 areg[4];
            #pragma unroll
            for (int p = 0; p < 4; ++p)
                areg[p] = *(const half8*)&Ab[(size_t)(p * 16 + arow) * V_ + acol * 8];

            floatx4 acc[2][2] = {};
            #pragma unroll 1
            for (int kt = 0; kt < NKT; ++kt) {
                __syncthreads();
                #pragma unroll
                for (int p = 0; p < 4; ++p)
                    *(half8*)&As[(p * 16 + arow) * 128 + ((acol ^ arow) * 8)] = areg[p];
                if (kt + 1 < NKT) {
                    #pragma unroll
                    for (int p = 0; p < 4; ++p)
                        areg[p] = *(const half8*)&Ab[(size_t)(p * 16 + arow) * V_ + (kt + 1) * 128 + acol * 8];
                }
                __syncthreads();
                ulonglong2 bw[2];
                #pragma unroll
                for (int nt2 = 0; nt2 < 2; ++nt2) {
                    int dloc = wn * 32 + nt2 * 16 + lrow;
                    bw[nt2] = *(const ulonglong2*)&Bb[dloc * VW + ((kt ^ (dloc & 15)) * 2)];
                }
                #pragma unroll
                for (int ks = 0; ks < 4; ++ks) {
                    half8 af[2];
                    #pragma unroll
                    for (int mt2 = 0; mt2 < 2; ++mt2) {
                        int row = wm * 32 + mt2 * 16 + lrow;
                        af[mt2] = *(const half8*)&As[row * 128 + (((ks * 4 + lq) ^ lrow) * 8)];
                    }
                    half8 bfrag[2];
                    #pragma unroll
                    for (int nt2 = 0; nt2 < 2; ++nt2) {
                        uint64_t w = (ks < 2) ? bw[nt2].x : bw[nt2].y;
                        uint32_t byte = (uint32_t)(w >> (((ks & 1) * 4 + lq) * 8)) & 0xFFu;
                        union { uint32_t u[4]; half8 h; } bu;
                        #pragma unroll
                        for (int i = 0; i < 4; ++i)
                            bu.u[i] = 0x3C003C00u ^ ((((byte >> (2 * i)) & 3u) * 0x40008000u) & 0x80008000u);
                        bfrag[nt2] = bu.h;
                    }
                    #pragma unroll
                    for (int mt2 = 0; mt2 < 2; ++mt2)
                        #pragma unroll
                        for (int nt2 = 0; nt2 < 2; ++nt2)
                            acc[mt2][nt2] = __builtin_amdgcn_mfma_f32_16x16x32_f16(
                                af[mt2], bfrag[nt2], acc[mt2][nt2], 0, 0, 0);
                }
            }
            __syncthreads();
            unsigned char* S = (unsigned char*)As;
            #pragma unroll
            for (int mt2 = 0; mt2 < 2; ++mt2)
                #pragma unroll
                for (int nt2 = 0; nt2 < 2; ++nt2)
                    #pragma unroll
                    for (int r = 0; r < 4; ++r) {
                        int row = wm * 32 + mt2 * 16 + lq * 4 + r;   // C/D row=quad*4+reg
                        int col = wn * 32 + nt2 * 16 + lrow;         // col=lane&15
                        S[row * 64 + col] = (acc[mt2][nt2][r] < 0.0f) ? 1 : 0;
                    }
            __syncthreads();
            if (tid < 64) {
                const uint64_t* Sw = (const uint64_t*)S;
                uint64_t m = 0;
                #pragma unroll
                for (int j = 0; j < 8; ++j) {
                    uint64_t w = Sw[tid * 8 + j];
                    m |= ((w * 0x0102040810204080ull) >> 56) << (8 * j);
                }
                int b = gm0 + tid;
                size_t widx = ((size_t)b * F_ + gf) * DW + gnt;
                uint64_t old = est_bits[widx];
                if (old != m) {
                    est_bits[widx] = m;
                    atomicXor((unsigned long long*)&nbc[(size_t)b * DW + gnt],
                              (unsigned long long)(old ^ m));
                    atomicOr(&bd, 1);
                }
            }
            __syncthreads();
            if (tid == 0 && bd) atomicOr(&flags[it], 1);
        }
        grid.sync();
        if (vflags[it] == 0) break;               // uniform: converged
    }

    // ------- argmax: key=(|sim/2|<<11)|(2047-v) -------------------------
    for (int vb = bx; vb < 512; vb += nblk) {
        int sf = vb & 3, sbg = (vb >> 2) & 15, svt = vb >> 6;
        uint64_t* eb = (uint64_t*)As;
        __syncthreads();
        #pragma unroll
        for (int j = 0; j < 2; ++j) {
            int idx = tid + j * 256;
            int bl = idx >> 6, w = idx & 63;
            eb[bl * DW + w] = est_bits[((size_t)(sbg * 8 + bl) * F_ + sf) * DW + w];
        }
        __syncthreads();
        int v = svt * 256 + tid;
        const uint64_t* cbrow = cb_bits + ((size_t)sf * V_ + v) * DW;
        int pc[8];
        #pragma unroll
        for (int bl = 0; bl < 8; ++bl) pc[bl] = 0;
        for (int w = 0; w < DW; w += 2) {
            ulonglong2 c2 = *(const ulonglong2*)&cbrow[w];
            #pragma unroll
            for (int bl = 0; bl < 8; ++bl) {
                ulonglong2 e2 = *(const ulonglong2*)&eb[bl * DW + w];
                pc[bl] += __popcll(e2.x ^ c2.x) + __popcll(e2.y ^ c2.y);
            }
        }
        int key[8];
        #pragma unroll
        for (int bl = 0; bl < 8; ++bl) {
            int m = 2048 - pc[bl]; if (m < 0) m = -m;
            key[bl] = (m << 11) | (2047 - v);
        }
        #pragma unroll
        for (int s = 1; s < 64; s <<= 1)
            #pragma unroll
            for (int bl = 0; bl < 8; ++bl) {
                int o = __shfl_xor(key[bl], s, 64);
                if (o > key[bl]) key[bl] = o;
            }
        if (lane == 0)
            for (int bl = 0; bl < 8; ++bl)
                atomicMax(&keys[(size_t)(sbg * 8 + bl) * F_ + sf], key[bl]);
    }
    grid.sync();

    if (bx == 0) {
        volatile int* vkeys = (volatile int*)keys;
        for (int t = tid; t < B_ * F_; t += 256)
            out[t] = 2047 - (vkeys[t] & 0x7FF);
        if (tid == 0) {
            int k = ITERS - 1;
            for (int i = 0; i < ITERS; ++i) if (vflags[i] == 0) { k = i; break; }
            out[B_ * F_] = k;
        }
    }
}

// ==================================================================
// Fallback path: proven Round-2 multi-kernel pipeline (absmax 0).
// ==================================================================
__global__ __launch_bounds__(256) void fb_pack(const float* __restrict__ x,
                                               uint16_t* __restrict__ bits16, int n16) {
    int t = blockIdx.x * blockDim.x + threadIdx.x;
    if (t >= n16) return;
    pack16(x, t, bits16);
}

__global__ void fb_packT(const uint64_t* __restrict__ cb_bits,
                         uint64_t* __restrict__ cbT) {
    int vw = blockIdx.x, dwg = blockIdx.y, f = blockIdx.z;
    int lane = threadIdx.x & 63;
    int dw = dwg * 4 + (threadIdx.x >> 6);
    uint64_t w = cb_bits[((size_t)f * V_ + vw * 64 + lane) * DW + dw];
    uint64_t r = 0;
    for (int d2 = 0; d2 < 64; ++d2) {
        uint64_t m = __ballot((unsigned)((w >> d2) & 1));
        if (lane == d2) r = m;
    }
    cbT[((size_t)f * D_ + dw * 64 + lane) * VW + vw] = r;
}

__global__ __launch_bounds__(256) void fb_sim(
        const uint64_t* __restrict__ cb_bits,
        const uint64_t* __restrict__ in_bits,
        const uint64_t* __restrict__ est_bits,
        _Float16* __restrict__ simf,
        const int* __restrict__ flags, int iter) {
    if (iter > 0 && flags[iter - 1] == 0) return;
    int vt = blockIdx.x, bt = blockIdx.y, f = blockIdx.z;
    int tid = threadIdx.x;
    __shared__ __align__(16) uint64_t nb[8][DW];
    #pragma unroll
    for (int j = 0; j < 2; ++j) {
        int idx = tid + j * 256;
        int bl = idx >> 6, w = idx & 63;
        int b = bt * 8 + bl;
        const uint64_t* e = est_bits + (size_t)b * F_ * DW;
        nb[bl][w] = in_bits[(size_t)b * DW + w] ^ e[0 * DW + w] ^ e[1 * DW + w]
                  ^ e[2 * DW + w] ^ e[3 * DW + w] ^ e[(size_t)f * DW + w];
    }
    __syncthreads();
    int v = vt * 256 + tid;
    int acc[8];
    #pragma unroll
    for (int bl = 0; bl < 8; ++bl) acc[bl] = 2048;
    const uint64_t* cbrow = cb_bits + ((size_t)f * V_ + v) * DW;
    for (int w = 0; w < DW; w += 2) {
        ulonglong2 c2 = *(const ulonglong2*)&cbrow[w];
        #pragma unroll
        for (int bl = 0; bl < 8; ++bl) {
            ulonglong2 n2 = *(const ulonglong2*)&nb[bl][w];
            acc[bl] -= __popcll(n2.x ^ c2.x) + __popcll(n2.y ^ c2.y);
        }
    }
    #pragma unroll
    for (int bl = 0; bl < 8; ++bl)
        simf[((size_t)f * B_ + bt * 8 + bl) * V_ + v] = (_Float16)acc[bl];
}

__global__ __launch_bounds__(256) void fb_gemm(
        const _Float16* __restrict__ simf,
        const uint64_t* __restrict__ cbT,
        uint64_t* __restrict__ est_bits,
        int* __restrict__ flags, int iter) {
    if (iter > 0 && flags[iter - 1] == 0) return;
    int nt = blockIdx.x, mt = blockIdx.y, f = blockIdx.z;
    int m0 = mt * 64;
    int tid = threadIdx.x;
    int lane = tid & 63, wave = tid >> 6;
    int lrow = lane & 15, lq = lane >> 4;
    int wm = wave & 1, wn = wave >> 1;

    __shared__ __align__(16) uint64_t Bb[64 * VW];
    __shared__ __align__(16) _Float16 As[64 * 128];
    __shared__ int bd;
    if (tid == 0) bd = 0;

    const uint64_t* bsrc = cbT + ((size_t)f * D_ + nt * 64) * VW;
    #pragma unroll
    for (int p = 0; p < 4; ++p) {
        int chunk = p * 256 + tid;
        int dloc = chunk >> 4, cw = chunk & 15;
        ulonglong2 val = *(const ulonglong2*)&bsrc[dloc * VW + cw * 2];
        *(ulonglong2*)&Bb[dloc * VW + ((cw ^ (dloc & 15)) * 2)] = val;
    }

    const _Float16* Ab = simf + (size_t)f * B_ * V_ + (size_t)m0 * V_;
    int arow = tid >> 4, acol = tid & 15;
    half8 areg[4];
    #pragma unroll
    for (int p = 0; p < 4; ++p)
        areg[p] = *(const half8*)&Ab[(size_t)(p * 16 + arow) * V_ + acol * 8];

    floatx4 acc[2][2] = {};
    #pragma unroll 1
    for (int kt = 0; kt < NKT; ++kt) {
        __syncthreads();
        #pragma unroll
        for (int p = 0; p < 4; ++p)
            *(half8*)&As[(p * 16 + arow) * 128 + ((acol ^ arow) * 8)] = areg[p];
        if (kt + 1 < NKT) {
            #pragma unroll
            for (int p = 0; p < 4; ++p)
                areg[p] = *(const half8*)&Ab[(size_t)(p * 16 + arow) * V_ + (kt + 1) * 128 + acol * 8];
        }
        __syncthreads();
        ulonglong2 bw[2];
        #pragma unroll
        for (int nt2 = 0; nt2 < 2; ++nt2) {
            int dloc = wn * 32 + nt2 * 16 + lrow;
            bw[nt2] = *(const ulonglong2*)&Bb[dloc * VW + ((kt ^ (dloc & 15)) * 2)];
        }
        #pragma unroll
        for (int ks = 0; ks < 4; ++ks) {
            half8 af[2];
            #pragma unroll
            for (int mt2 = 0; mt2 < 2; ++mt2) {
                int row = wm * 32 + mt2 * 16 + lrow;
                af[mt2] = *(const half8*)&As[row * 128 + (((ks * 4 + lq) ^ lrow) * 8)];
            }
            half8 bfrag[2];
            #pragma unroll
            for (int nt2 = 0; nt2 < 2; ++nt2) {
                uint64_t w = (ks < 2) ? bw[nt2].x : bw[nt2].y;
                uint32_t byte = (uint32_t)(w >> (((ks & 1) * 4 + lq) * 8)) & 0xFFu;
                union { uint32_t u[4]; half8 h; } bu;
                #pragma unroll
                for (int i = 0; i < 4; ++i)
                    bu.u[i] = 0x3C003C00u ^ ((((byte >> (2 * i)) & 3u) * 0x40008000u) & 0x80008000u);
                bfrag[nt2] = bu.h;
            }
            #pragma unroll
            for (int mt2 = 0; mt2 < 2; ++mt2)
                #pragma unroll
                for (int nt2 = 0; nt2 < 2; ++nt2)
                    acc[mt2][nt2] = __builtin_amdgcn_mfma_f32_16x16x32_f16(
                        af[mt2], bfrag[nt2], acc[mt2][nt2], 0, 0, 0);
        }
    }
    __syncthreads();
    unsigned char* S = (unsigned char*)As;
    #pragma unroll
    for (int mt2 = 0; mt2 < 2; ++mt2)
        #pragma unroll
        for (int nt2 = 0; nt2 < 2; ++nt2)
            #pragma unroll
            for (int r = 0; r < 4; ++r) {
                int row = wm * 32 + mt2 * 16 + lq * 4 + r;
                int col = wn * 32 + nt2 * 16 + lrow;
                S[row * 64 + col] = (acc[mt2][nt2][r] < 0.0f) ? 1 : 0;
            }
    __syncthreads();
    if (tid < 64) {
        const uint64_t* Sw = (const uint64_t*)S;
        uint64_t m = 0;
        #pragma unroll
        for (int j = 0; j < 8; ++j) {
            uint64_t w = Sw[tid * 8 + j];
            m |= ((w * 0x0102040810204080ull) >> 56) << (8 * j);
        }
        size_t widx = ((size_t)(m0 + tid) * F_ + f) * DW + nt;
        uint64_t old = est_bits[widx];
        est_bits[widx] = m;
        if (old != m) atomicOr(&bd, 1);
    }
    __syncthreads();
    if (tid == 0 && bd) atomicOr(&flags[iter], 1);
}

__global__ __launch_bounds__(256) void fb_argmax(
        const uint64_t* __restrict__ cb_bits,
        const uint64_t* __restrict__ est_bits,
        int* __restrict__ keys) {
    int vt = blockIdx.x, bg = blockIdx.y, f = blockIdx.z;
    int tid = threadIdx.x, lane = tid & 63;
    __shared__ __align__(16) uint64_t eb[16][DW];
    #pragma unroll
    for (int j = 0; j < 4; ++j) {
        int idx = tid + j * 256;
        int bl = idx >> 6, w = idx & 63;
        eb[bl][w] = est_bits[((size_t)(bg * 16 + bl) * F_ + f) * DW + w];
    }
    __syncthreads();
    int v = vt * 256 + tid;
    const uint64_t* cbrow = cb_bits + ((size_t)f * V_ + v) * DW;
    int pc[16];
    #pragma unroll
    for (int bl = 0; bl < 16; ++bl) pc[bl] = 0;
    for (int w = 0; w < DW; w += 2) {
        ulonglong2 c2 = *(const ulonglong2*)&cbrow[w];
        #pragma unroll
        for (int bl = 0; bl < 16; ++bl) {
            ulonglong2 e2 = *(const ulonglong2*)&eb[bl][w];
            pc[bl] += __popcll(e2.x ^ c2.x) + __popcll(e2.y ^ c2.y);
        }
    }
    int key[16];
    #pragma unroll
    for (int bl = 0; bl < 16; ++bl) {
        int m = 2048 - pc[bl]; if (m < 0) m = -m;
        key[bl] = (m << 11) | (2047 - v);
    }
    #pragma unroll
    for (int s = 1; s < 64; s <<= 1)
        #pragma unroll
        for (int bl = 0; bl < 16; ++bl) {
            int o = __shfl_xor(key[bl], s, 64);
            if (o > key[bl]) key[bl] = o;
        }
    if (lane == 0)
        for (int bl = 0; bl < 16; ++bl)
            atomicMax(&keys[(size_t)(bg * 16 + bl) * F_ + f], key[bl]);
}

__global__ void fb_final(const int* __restrict__ keys, const int* __restrict__ flags,
                         int* __restrict__ out) {
    int tid = blockIdx.x * blockDim.x + threadIdx.x;
    if (tid < B_ * F_) out[tid] = 2047 - (keys[tid] & 0x7FF);
    if (tid == 0) {
        int k = ITERS - 1;
        for (int i = 0; i < ITERS; ++i) if (flags[i] == 0) { k = i; break; }
        out[B_ * F_] = k;
    }
}

// ==================================================================
extern "C" void kernel_launch(void* const* d_in, const int* in_sizes, int n_in,
                              void* d_out, int out_size, void* d_ws, size_t ws_size,
                              hipStream_t stream) {
    const float* inputs = (const float*)d_in[0];   // (B, D)
    const float* inite  = (const float*)d_in[1];   // (B, F, D)
    const float* cb     = (const float*)d_in[2];   // (F, V, D)
    int* out = (int*)d_out;                        // 512 outcome + 1 k

    char* ws = (char*)d_ws;
    uint64_t* cb_bits  = (uint64_t*)ws;  ws += (size_t)F_ * V_ * DW * 8;   // 4 MiB
    uint64_t* cbT_bits = (uint64_t*)ws;  ws += (size_t)F_ * D_ * VW * 8;   // 4 MiB
    uint64_t* est_bits = (uint64_t*)ws;  ws += (size_t)B_ * F_ * DW * 8;   // 256 KiB
    uint64_t* in_bits  = (uint64_t*)ws;  ws += (size_t)B_ * DW * 8;        // 64 KiB
    uint64_t* nbc      = (uint64_t*)ws;  ws += (size_t)B_ * DW * 8;        // 64 KiB
    _Float16* simf     = (_Float16*)ws;  ws += (size_t)F_ * B_ * V_ * 2;   // 2 MiB
    int*      flags    = (int*)ws;       ws += 32 * 4;
    int*      keys     = (int*)ws;       ws += B_ * F_ * 4;

    hipMemsetAsync(flags, 0, (32 + B_ * F_) * sizeof(int), stream);

    void* args[] = { &inputs, &inite, &cb, &out,
                     &cb_bits, &cbT_bits, &est_bits, &in_bits,
                     &nbc, &simf, &flags, &keys };

    bool done = false;
    int dev = 0, coop = 0;
    if (hipGetDevice(&dev) == hipSuccess &&
        hipDeviceGetAttribute(&coop, hipDeviceAttributeCooperativeLaunch, dev) == hipSuccess &&
        coop) {
        if (hipLaunchCooperativeKernel((const void*)k_fused, dim3(512), dim3(256),
                                       args, 0, stream) == hipSuccess) done = true;
        else if (hipLaunchCooperativeKernel((const void*)k_fused, dim3(256), dim3(256),
                                            args, 0, stream) == hipSuccess) done = true;
    }
    if (!done) {
        fb_pack<<<(F_ * V_ * D_) / 16 / 256, 256, 0, stream>>>(cb,     (uint16_t*)cb_bits,  F_ * V_ * D_ / 16);
        fb_pack<<<(B_ * F_ * D_) / 16 / 256, 256, 0, stream>>>(inite,  (uint16_t*)est_bits, B_ * F_ * D_ / 16);
        fb_pack<<<(B_ * D_) / 16 / 256,      256, 0, stream>>>(inputs, (uint16_t*)in_bits,  B_ * D_ / 16);
        fb_packT<<<dim3(32, 16, 4), 256, 0, stream>>>(cb_bits, cbT_bits);
        for (int i = 0; i < ITERS; ++i) {
            fb_sim<<<dim3(8, 16, 4), 256, 0, stream>>>(cb_bits, in_bits, est_bits, simf, flags, i);
            fb_gemm<<<dim3(64, 2, 4), 256, 0, stream>>>(simf, cbT_bits, est_bits, flags, i);
        }
        fb_argmax<<<dim3(8, 8, 4), 256, 0, stream>>>(cb_bits, est_bits, keys);
        fb_final<<<2, 256, 0, stream>>>(keys, flags, out);
    }
}

// Round 6
// 1202.619 us; speedup vs baseline: 5.0868x; 5.0868x over previous
//
#include <hip/hip_runtime.h>
#include <hip/hip_bf16.h>
#include <stdint.h>

#define B_    128
#define F_    4
#define V_    2048
#define D_    4096
#define DW    64      // D/64 bit-words per (b,f) row
#define VW    32      // V/64 bit-words per d column
#define ITERS 20
#define NKT   8       // K tiles of 256 over V=2048

typedef _Float16 half8 __attribute__((ext_vector_type(8)));
typedef float   floatx4 __attribute__((ext_vector_type(4)));

__device__ __forceinline__ void pack16(const float* __restrict__ x, int t,
                                       uint16_t* __restrict__ dst) {
    const float4* p = (const float4*)(x + (size_t)t * 16);
    unsigned m = 0;
    #pragma unroll
    for (int j = 0; j < 4; ++j) {
        float4 v = p[j];
        m |= (v.x < 0.0f ? 1u : 0u) << (4 * j + 0);
        m |= (v.y < 0.0f ? 1u : 0u) << (4 * j + 1);
        m |= (v.z < 0.0f ? 1u : 0u) << (4 * j + 2);
        m |= (v.w < 0.0f ? 1u : 0u) << (4 * j + 3);
    }
    dst[t] = (uint16_t)m;
}

// ------------------------------------------------------------------
// Prep 1: pack cb/inite/inputs sign bits; zero flags & keys.
// grid 2048 x 256.
// ------------------------------------------------------------------
__global__ __launch_bounds__(256) void k_packall(
        const float* __restrict__ cb, const float* __restrict__ inite,
        const float* __restrict__ inputs,
        uint16_t* __restrict__ cbb, uint16_t* __restrict__ e16,
        uint16_t* __restrict__ i16, int* __restrict__ flags,
        int* __restrict__ keys) {
    int gtid = blockIdx.x * 256 + threadIdx.x, gsz = gridDim.x * 256;
    for (int t = gtid; t < F_ * V_ * D_ / 16; t += gsz) pack16(cb, t, cbb);
    for (int t = gtid; t < B_ * F_ * D_ / 16; t += gsz) pack16(inite, t, e16);
    for (int t = gtid; t < B_ * D_ / 16; t += gsz) pack16(inputs, t, i16);
    if (gtid < ITERS) flags[gtid] = 0;
    if (gtid >= 32 && gtid < 32 + B_ * F_) keys[gtid - 32] = 0;
}

// ------------------------------------------------------------------
// Prep 2: transpose cb bits -> cbT[f][d][vwords]; init
// nbc[b][w] = in ^ e0^e1^e2^e3.  grid 2048 x 256.
// ------------------------------------------------------------------
__global__ __launch_bounds__(256) void k_prep(
        const uint64_t* __restrict__ cb_bits, uint64_t* __restrict__ cbT,
        const uint64_t* __restrict__ in_bits, const uint64_t* __restrict__ est_bits,
        uint64_t* __restrict__ nbc) {
    int u = blockIdx.x, tid = threadIdx.x;
    int lane = tid & 63;
    int vw = u & 31, dwg = (u >> 5) & 15, f = u >> 9;
    int dw = dwg * 4 + (tid >> 6);
    uint64_t w = cb_bits[((size_t)f * V_ + vw * 64 + lane) * DW + dw];
    uint64_t r = 0;
    for (int d2 = 0; d2 < 64; ++d2) {
        uint64_t m = __ballot((unsigned)((w >> d2) & 1));
        if (lane == d2) r = m;
    }
    cbT[((size_t)f * D_ + dw * 64 + lane) * VW + vw] = r;

    int gtid = u * 256 + tid;
    if (gtid < B_ * DW) {
        int b = gtid >> 6, ww = gtid & 63;
        const uint64_t* e = est_bits + (size_t)b * F_ * DW;
        nbc[gtid] = in_bits[gtid] ^ e[ww] ^ e[DW + ww] ^ e[2 * DW + ww] ^ e[3 * DW + ww];
    }
}

// ------------------------------------------------------------------
// sim[b,f,v] = 2048 - popc(nbc[b] ^ est[b][f] ^ cb[f][v]).  No LDS:
// nbc/est rows are wave-uniform -> scalar loads.  4 b per thread.
// grid (vt=8, bg=32, f=4) = 1024 blocks, 256 thr.
// ------------------------------------------------------------------
__global__ __launch_bounds__(256, 4) void k_sim(
        const uint64_t* __restrict__ cb_bits,
        const uint64_t* __restrict__ nbc,
        const uint64_t* __restrict__ est_bits,
        _Float16* __restrict__ simf,
        const int* __restrict__ flags, int iter) {
    if (iter > 0 && flags[iter - 1] == 0) return;
    int vt = blockIdx.x, bg = blockIdx.y, f = blockIdx.z;
    int tid = threadIdx.x;
    int v = vt * 256 + tid;
    const uint64_t* cbrow = cb_bits + ((size_t)f * V_ + v) * DW;
    int acc[4] = {2048, 2048, 2048, 2048};
    #pragma unroll 1
    for (int h = 0; h < 2; ++h) {                 // 2 halves x 32 words
        ulonglong2 c[16];
        #pragma unroll
        for (int j = 0; j < 16; ++j) c[j] = *(const ulonglong2*)&cbrow[h * 32 + 2 * j];
        #pragma unroll
        for (int bb = 0; bb < 4; ++bb) {
            int b = bg * 4 + bb;
            const uint64_t* np = nbc + (size_t)b * DW + h * 32;               // uniform
            const uint64_t* ep = est_bits + ((size_t)b * F_ + f) * DW + h * 32; // uniform
            int s = 0;
            #pragma unroll
            for (int j = 0; j < 16; ++j) {
                uint64_t n0 = np[2 * j]     ^ ep[2 * j];
                uint64_t n1 = np[2 * j + 1] ^ ep[2 * j + 1];
                s += __popcll(c[j].x ^ n0) + __popcll(c[j].y ^ n1);
            }
            acc[bb] -= s;
        }
    }
    #pragma unroll
    for (int bb = 0; bb < 4; ++bb)
        simf[((size_t)f * B_ + bg * 4 + bb) * V_ + v] = (_Float16)acc[bb];  // exact
}

// ------------------------------------------------------------------
// est = sign(sim @ cb^T).  BM=64 BN=64 BK=256 (8 kt, 16 barriers).
// grid (nt=64, mt=2, f=4) = 512 blocks, 256 thr, wave tile 32x32.
// Epilogue maintains est_bits + nbc (atomicXor) + flags.
// ------------------------------------------------------------------
__global__ __launch_bounds__(256, 2) void k_gemm(
        const _Float16* __restrict__ simf,
        const uint64_t* __restrict__ cbT,
        uint64_t* __restrict__ est_bits,
        uint64_t* __restrict__ nbc,
        int* __restrict__ flags, int iter) {
    if (iter > 0 && flags[iter - 1] == 0) return;
    int nt = blockIdx.x, mt = blockIdx.y, f = blockIdx.z;
    int m0 = mt * 64;
    int tid = threadIdx.x;
    int lane = tid & 63, wave = tid >> 6;
    int lrow = lane & 15, lq = lane >> 4;
    int wm = wave & 1, wn = wave >> 1;

    __shared__ __align__(16) uint64_t Bb[64 * VW];      // 16 KB bit panel
    __shared__ __align__(16) _Float16 As[64 * 256];     // 32 KB A tile
    __shared__ int bd;
    if (tid == 0) bd = 0;

    // preload B bit-panel: 64 d-rows x 32 vwords, swizzled 16B chunks
    const uint64_t* bsrc = cbT + ((size_t)f * D_ + nt * 64) * VW;
    #pragma unroll
    for (int p = 0; p < 4; ++p) {
        int chunk = p * 256 + tid;
        int dloc = chunk >> 4, cw = chunk & 15;
        ulonglong2 val = *(const ulonglong2*)&bsrc[dloc * VW + cw * 2];
        *(ulonglong2*)&Bb[dloc * VW + ((cw ^ (dloc & 15)) * 2)] = val;
    }

    const _Float16* Ab = simf + (size_t)f * B_ * V_ + (size_t)m0 * V_;
    int arow = tid >> 5, acol = tid & 31;      // 8 rows x 32 chunks per pass
    half8 areg[8];
    #pragma unroll
    for (int p = 0; p < 8; ++p)
        areg[p] = *(const half8*)&Ab[(size_t)(p * 8 + arow) * V_ + acol * 8];

    floatx4 acc[2][2] = {};
    #pragma unroll 1
    for (int kt = 0; kt < NKT; ++kt) {
        __syncthreads();
        #pragma unroll
        for (int p = 0; p < 8; ++p)
            *(half8*)&As[(p * 8 + arow) * 256 + ((acol ^ ((p * 8 + arow) & 15)) * 8)] = areg[p];
        if (kt + 1 < NKT) {
            #pragma unroll
            for (int p = 0; p < 8; ++p)
                areg[p] = *(const half8*)&Ab[(size_t)(p * 8 + arow) * V_ + (kt + 1) * 256 + acol * 8];
        }
        __syncthreads();

        // B bits for this kt: 4 u64 words (256 v) per d-row
        uint64_t bwv[2][4];
        #pragma unroll
        for (int nt2 = 0; nt2 < 2; ++nt2) {
            int dloc = wn * 32 + nt2 * 16 + lrow;
            #pragma unroll
            for (int cc = 0; cc < 2; ++cc) {
                ulonglong2 t2 = *(const ulonglong2*)&Bb[dloc * VW + (((kt * 2 + cc) ^ (dloc & 15)) * 2)];
                bwv[nt2][cc * 2] = t2.x; bwv[nt2][cc * 2 + 1] = t2.y;
            }
        }
        #pragma unroll
        for (int ks = 0; ks < 8; ++ks) {
            half8 af[2];
            #pragma unroll
            for (int mt2 = 0; mt2 < 2; ++mt2) {
                int row = wm * 32 + mt2 * 16 + lrow;
                af[mt2] = *(const half8*)&As[row * 256 + (((ks * 4 + lq) ^ (row & 15)) * 8)];
            }
            half8 bfrag[2];
            #pragma unroll
            for (int nt2 = 0; nt2 < 2; ++nt2) {
                uint64_t w = bwv[nt2][ks >> 1];
                uint32_t byte = (uint32_t)(w >> (((ks & 1) * 4 + lq) * 8)) & 0xFFu;
                union { uint32_t u[4]; half8 h; } bu;
                #pragma unroll
                for (int i = 0; i < 4; ++i)
                    bu.u[i] = 0x3C003C00u ^ ((((byte >> (2 * i)) & 3u) * 0x40008000u) & 0x80008000u);
                bfrag[nt2] = bu.h;
            }
            #pragma unroll
            for (int mt2 = 0; mt2 < 2; ++mt2)
                #pragma unroll
                for (int nt2 = 0; nt2 < 2; ++nt2)
                    acc[mt2][nt2] = __builtin_amdgcn_mfma_f32_16x16x32_f16(
                        af[mt2], bfrag[nt2], acc[mt2][nt2], 0, 0, 0);
        }
    }

    // epilogue: hardsign -> LDS bytes -> u64 word per b-row; update nbc
    __syncthreads();
    unsigned char* S = (unsigned char*)As;
    #pragma unroll
    for (int mt2 = 0; mt2 < 2; ++mt2)
        #pragma unroll
        for (int nt2 = 0; nt2 < 2; ++nt2)
            #pragma unroll
            for (int r = 0; r < 4; ++r) {
                int row = wm * 32 + mt2 * 16 + lq * 4 + r;   // C/D row = quad*4+reg
                int col = wn * 32 + nt2 * 16 + lrow;         // col = lane&15
                S[row * 64 + col] = (acc[mt2][nt2][r] < 0.0f) ? 1 : 0;  // sign(0)=+1
            }
    __syncthreads();
    if (tid < 64) {
        const uint64_t* Sw = (const uint64_t*)S;
        uint64_t m = 0;
        #pragma unroll
        for (int j = 0; j < 8; ++j) {
            uint64_t w = Sw[tid * 8 + j];
            m |= ((w * 0x0102040810204080ull) >> 56) << (8 * j);
        }
        int b = m0 + tid;
        size_t widx = ((size_t)b * F_ + f) * DW + nt;
        uint64_t old = est_bits[widx];
        if (old != m) {
            est_bits[widx] = m;
            atomicXor((unsigned long long*)&nbc[(size_t)b * DW + nt],
                      (unsigned long long)(old ^ m));
            atomicOr(&bd, 1);
        }
    }
    __syncthreads();
    if (tid == 0 && bd) atomicOr(&flags[iter], 1);
}

// ------------------------------------------------------------------
// argmax_v |sim|: key=(|2048-pc|<<11)|(2047-v), atomicMax.  Uniform
// scalar loads for est rows (no LDS).  grid (8,8,4), 16 b per block.
// ------------------------------------------------------------------
__global__ __launch_bounds__(256) void k_argmax(
        const uint64_t* __restrict__ cb_bits,
        const uint64_t* __restrict__ est_bits,
        int* __restrict__ keys) {
    int vt = blockIdx.x, bg = blockIdx.y, f = blockIdx.z;
    int tid = threadIdx.x, lane = tid & 63;
    int v = vt * 256 + tid;
    const uint64_t* cbrow = cb_bits + ((size_t)f * V_ + v) * DW;
    int pc[16];
    #pragma unroll
    for (int bl = 0; bl < 16; ++bl) pc[bl] = 0;
    #pragma unroll 1
    for (int h = 0; h < 4; ++h) {                 // 4 quarters x 16 words
        ulonglong2 c[8];
        #pragma unroll
        for (int j = 0; j < 8; ++j) c[j] = *(const ulonglong2*)&cbrow[h * 16 + 2 * j];
        #pragma unroll
        for (int bl = 0; bl < 16; ++bl) {
            const uint64_t* ep = est_bits + ((size_t)(bg * 16 + bl) * F_ + f) * DW + h * 16;
            int s = 0;
            #pragma unroll
            for (int j = 0; j < 8; ++j)
                s += __popcll(c[j].x ^ ep[2 * j]) + __popcll(c[j].y ^ ep[2 * j + 1]);
            pc[bl] += s;
        }
    }
    int key[16];
    #pragma unroll
    for (int bl = 0; bl < 16; ++bl) {
        int m = 2048 - pc[bl]; if (m < 0) m = -m;
        key[bl] = (m << 11) | (2047 - v);
    }
    #pragma unroll
    for (int s = 1; s < 64; s <<= 1)
        #pragma unroll
        for (int bl = 0; bl < 16; ++bl) {
            int o = __shfl_xor(key[bl], s, 64);
            if (o > key[bl]) key[bl] = o;
        }
    if (lane == 0)
        for (int bl = 0; bl < 16; ++bl)
            atomicMax(&keys[(size_t)(bg * 16 + bl) * F_ + f], key[bl]);
}

__global__ void k_final(const int* __restrict__ keys, const int* __restrict__ flags,
                        int* __restrict__ out) {
    int tid = blockIdx.x * blockDim.x + threadIdx.x;
    if (tid < B_ * F_) out[tid] = 2047 - (keys[tid] & 0x7FF);
    if (tid == 0) {
        int k = ITERS - 1;
        for (int i = 0; i < ITERS; ++i) if (flags[i] == 0) { k = i; break; }
        out[B_ * F_] = k;
    }
}

// ------------------------------------------------------------------
extern "C" void kernel_launch(void* const* d_in, const int* in_sizes, int n_in,
                              void* d_out, int out_size, void* d_ws, size_t ws_size,
                              hipStream_t stream) {
    const float* inputs = (const float*)d_in[0];   // (B, D)
    const float* inite  = (const float*)d_in[1];   // (B, F, D)
    const float* cb     = (const float*)d_in[2];   // (F, V, D)
    int* out = (int*)d_out;                        // 512 outcome + 1 k

    char* ws = (char*)d_ws;
    uint64_t* cb_bits  = (uint64_t*)ws;  ws += (size_t)F_ * V_ * DW * 8;   // 4 MiB
    uint64_t* cbT_bits = (uint64_t*)ws;  ws += (size_t)F_ * D_ * VW * 8;   // 4 MiB
    uint64_t* est_bits = (uint64_t*)ws;  ws += (size_t)B_ * F_ * DW * 8;   // 256 KiB
    uint64_t* in_bits  = (uint64_t*)ws;  ws += (size_t)B_ * DW * 8;        // 64 KiB
    uint64_t* nbc      = (uint64_t*)ws;  ws += (size_t)B_ * DW * 8;        // 64 KiB
    _Float16* simf     = (_Float16*)ws;  ws += (size_t)F_ * B_ * V_ * 2;   // 2 MiB
    int*      flags    = (int*)ws;       ws += 32 * 4;
    int*      keys     = (int*)ws;       ws += B_ * F_ * 4;

    k_packall<<<2048, 256, 0, stream>>>(cb, inite, inputs,
        (uint16_t*)cb_bits, (uint16_t*)est_bits, (uint16_t*)in_bits, flags, keys);
    k_prep<<<2048, 256, 0, stream>>>(cb_bits, cbT_bits, in_bits, est_bits, nbc);

    for (int i = 0; i < ITERS; ++i) {
        k_sim<<<dim3(8, 32, 4), 256, 0, stream>>>(cb_bits, nbc, est_bits, simf, flags, i);
        k_gemm<<<dim3(64, 2, 4), 256, 0, stream>>>(simf, cbT_bits, est_bits, nbc, flags, i);
    }
    k_argmax<<<dim3(8, 8, 4), 256, 0, stream>>>(cb_bits, est_bits, keys);
    k_final<<<2, 256, 0, stream>>>(keys, flags, out);
}